// Round 3
// baseline (951.220 us; speedup 1.0000x reference)
//
#include <hip/hip_runtime.h>

// QGrouping fused pipeline (audited r2; structure unchanged from r1).
//   weights = x @ (Wq@Wk)^T + (Wq@bk+bq)   -- key[N,100] never materialized
//   e = exp(weights)  (NO max-subtract: |w| <~ 3 by construction, f32 exp safe;
//                      softmax is shift-invariant so result matches reference)
//   embs_unnorm[b,k,v] = seg-sum e*val ; segsum[b,k] = seg-sum e   (fused in k_main;
//                      val[N,32] lives only in registers/LDS -- never hits HBM)
//   k_final: embs /= segsum ; norm_w = e / segsum
// d_out layout: embs[128*8*32] then norm_w[N*8].
// Roofline: mandatory traffic ~570 MB -> ~90 us @ 6.3 TB/s; VALU ~78 us. Memory-bound.

#define NSEG 128
#define KQ 8
#define VD 32
#define NOUT 40    // KQ + VD
#define INDIM 256
#define ROWS 128   // rows per block (block = 128 threads, 2 waves)
#define CCH 32     // x columns staged per chunk
#define XSTR 36    // CCH + 4 pad: row stride 144B = 4-bank shift -> conflict-free b128
#define ESTR 12    // KQ + 4 pad
#define VSTR 36    // VD + 4 pad
#define SMEMF (ROWS * (ESTR + VSTR))   // 6144 floats = 24 KB (>= ROWS*XSTR = 4608)

// ---------------- setup: combined weights + zero embs/segsum ----------------
__global__ __launch_bounds__(256) void k_setup(
    const float* __restrict__ Wk, const float* __restrict__ bk,
    const float* __restrict__ Wq, const float* __restrict__ bq,
    const float* __restrict__ Wv, const float* __restrict__ bv,
    float* __restrict__ WO, float* __restrict__ bo,
    float* __restrict__ segsum, float* __restrict__ embs) {
    int b = blockIdx.x;
    int c = threadIdx.x;
    if (b < NOUT) {
        if (b < KQ) {
            float a = 0.f;
            for (int j = 0; j < 100; ++j) a = fmaf(Wq[b * 100 + j], Wk[j * INDIM + c], a);
            WO[b * INDIM + c] = a;
            if (c == 0) {
                float s = bq[b];
                for (int j = 0; j < 100; ++j) s = fmaf(Wq[b * 100 + j], bk[j], s);
                bo[b] = s;
            }
        } else {
            int v = b - KQ;
            WO[b * INDIM + c] = Wv[v * INDIM + c];
            if (c == 0) bo[b] = bv[v];
        }
    } else {
        int i = (b - NOUT) * 256 + c;
        if (i < NSEG * KQ * VD) {
            embs[i] = 0.f;
        } else {
            int j = i - NSEG * KQ * VD;
            if (j < NSEG * KQ) segsum[j] = 0.f;
        }
    }
}

// ---------------- main: GEMV + exp + fused seg-reduction ----------------
__global__ __launch_bounds__(ROWS, 3) void k_main(
    const float* __restrict__ x, const int* __restrict__ batch,
    const float* __restrict__ WO, const float* __restrict__ bo,
    float* __restrict__ eout,          // d_out norm_w region: holds e for now
    float* __restrict__ segsum, float* __restrict__ embs, int N) {
    __shared__ float smem[SMEMF];
    __shared__ int sg[ROWS];
    const int tid = threadIdx.x;
    const int row0 = blockIdx.x * ROWS;
    const int row = row0 + tid;
    const bool valid = row < N;

    sg[tid] = valid ? batch[row] : batch[N - 1];   // tail rows: e=0, seg value harmless

    float acc[NOUT];
#pragma unroll
    for (int o = 0; o < NOUT; ++o) acc[o] = bo[o];   // uniform -> s_load

    float* xs = smem;
    for (int cc = 0; cc < INDIM; cc += CCH) {
        __syncthreads();   // protect xs from previous phase's readers
#pragma unroll
        for (int i = 0; i < ROWS * CCH / 4 / ROWS; ++i) {   // 8 float4 per thread
            int g = i * ROWS + tid;
            int r = g >> 3;            // 8 threads per row: 128B contiguous per row
            int c = (g & 7) << 2;
            float4 v = make_float4(0.f, 0.f, 0.f, 0.f);
            int rr = row0 + r;
            if (rr < N) v = *(const float4*)&x[(size_t)rr * INDIM + cc + c];
            *(float4*)&xs[r * XSTR + c] = v;
        }
        __syncthreads();
#pragma unroll
        for (int c4 = 0; c4 < CCH; c4 += 4) {
            float4 xv = *(const float4*)&xs[tid * XSTR + c4];
            const float* wp = &WO[cc + c4];
#pragma unroll
            for (int o = 0; o < NOUT; ++o) {
                const float* w = wp + o * INDIM;   // uniform -> scalar loads
                acc[o] = fmaf(xv.x, w[0],
                         fmaf(xv.y, w[1],
                         fmaf(xv.z, w[2],
                         fmaf(xv.w, w[3], acc[o]))));
            }
        }
    }
    __syncthreads();   // done reading xs; smem becomes es/vs

    // e = exp(w); tail rows contribute exact zeros
    float e[KQ];
#pragma unroll
    for (int k = 0; k < KQ; ++k) e[k] = valid ? expf(acc[k]) : 0.f;

    if (valid) {   // stash unnormalized e; k_final normalizes in place
        *(float4*)&eout[(size_t)row * KQ]     = make_float4(e[0], e[1], e[2], e[3]);
        *(float4*)&eout[(size_t)row * KQ + 4] = make_float4(e[4], e[5], e[6], e[7]);
    }

    float* es = smem;                  // [ROWS][ESTR]
    float* vs = smem + ROWS * ESTR;    // [ROWS][VSTR]
    *(float4*)&es[tid * ESTR]     = make_float4(e[0], e[1], e[2], e[3]);
    *(float4*)&es[tid * ESTR + 4] = make_float4(e[4], e[5], e[6], e[7]);
#pragma unroll
    for (int i = 0; i < VD; i += 4) {
        float4 v = valid ? make_float4(acc[KQ + i], acc[KQ + i + 1],
                                       acc[KQ + i + 2], acc[KQ + i + 3])
                         : make_float4(0.f, 0.f, 0.f, 0.f);
        *(float4*)&vs[tid * VSTR + i] = v;
    }
    __syncthreads();

    // thread owns (k0,vcol) and (k0+4,vcol); serial over the block's sorted rows.
    // es read: 32-lane broadcast. vs read: 32 distinct banks. Conflict-free.
    const int k0 = tid >> 5;       // 0..3
    const int vcol = tid & 31;
    float a0 = 0.f, a1 = 0.f, s0 = 0.f, s1 = 0.f;
    int cur = sg[0];
    for (int r = 0; r < ROWS; ++r) {
        int s = sg[r];                       // block-uniform (sorted segments)
        if (s != cur) {                      // rare (segment ~3900 rows >> 128)
            atomicAdd(&embs[cur * (KQ * VD) + k0 * VD + vcol], a0);
            atomicAdd(&embs[cur * (KQ * VD) + (k0 + 4) * VD + vcol], a1);
            if (vcol == 0) {
                atomicAdd(&segsum[cur * KQ + k0], s0);
                atomicAdd(&segsum[cur * KQ + k0 + 4], s1);
            }
            a0 = a1 = s0 = s1 = 0.f;
            cur = s;
        }
        float ev0 = es[r * ESTR + k0];
        float ev1 = es[r * ESTR + k0 + 4];
        float vvv = vs[r * VSTR + vcol];
        a0 = fmaf(ev0, vvv, a0);
        a1 = fmaf(ev1, vvv, a1);
        s0 += ev0;
        s1 += ev1;
    }
    atomicAdd(&embs[cur * (KQ * VD) + k0 * VD + vcol], a0);
    atomicAdd(&embs[cur * (KQ * VD) + (k0 + 4) * VD + vcol], a1);
    if (vcol == 0) {
        atomicAdd(&segsum[cur * KQ + k0], s0);
        atomicAdd(&segsum[cur * KQ + k0 + 4], s1);
    }
}

// ---------------- final: normalize embs and norm_w ----------------
__global__ __launch_bounds__(256) void k_final(
    float* __restrict__ wnorm, const int* __restrict__ batch,
    const float* __restrict__ segsum, float* __restrict__ embs, int N) {
    int gid = blockIdx.x * 256 + threadIdx.x;
    if (gid < NSEG * KQ * VD) {
        embs[gid] = embs[gid] / segsum[gid >> 5];   // idx = b*256+k*32+v -> (b*8+k)=gid>>5
    }
    if (gid < N) {
        int s = batch[gid];
        float4 e0 = *(float4*)&wnorm[(size_t)gid * KQ];
        float4 e1 = *(float4*)&wnorm[(size_t)gid * KQ + 4];
        const float* ss = &segsum[s * KQ];
        e0.x /= ss[0]; e0.y /= ss[1]; e0.z /= ss[2]; e0.w /= ss[3];
        e1.x /= ss[4]; e1.y /= ss[5]; e1.z /= ss[6]; e1.w /= ss[7];
        *(float4*)&wnorm[(size_t)gid * KQ]     = e0;
        *(float4*)&wnorm[(size_t)gid * KQ + 4] = e1;
    }
}

extern "C" void kernel_launch(void* const* d_in, const int* in_sizes, int n_in,
                              void* d_out, int out_size, void* d_ws, size_t ws_size,
                              hipStream_t stream) {
    const float* x   = (const float*)d_in[0];
    const int* batch = (const int*)d_in[1];
    const float* Wk  = (const float*)d_in[2];
    const float* bk  = (const float*)d_in[3];
    const float* Wq  = (const float*)d_in[4];
    const float* bq  = (const float*)d_in[5];
    const float* Wv  = (const float*)d_in[6];
    const float* bv  = (const float*)d_in[7];
    const int N = in_sizes[1];

    float* ws_f = (float*)d_ws;
    float* WO = ws_f;                        // 40*256 floats
    float* bo = ws_f + NOUT * INDIM;         // 40
    float* segsum = ws_f + NOUT * INDIM + NOUT + 8;   // 1024 floats, 16B-aligned

    float* embs  = (float*)d_out;                       // [128*8*32]
    float* wnorm = (float*)d_out + NSEG * KQ * VD;      // [N*8]: e -> norm_w in place

    {
        int nb = NOUT + (NSEG * KQ * VD + NSEG * KQ + 255) / 256;   // 40 + 132
        k_setup<<<nb, 256, 0, stream>>>(Wk, bk, Wq, bq, Wv, bv, WO, bo, segsum, embs);
    }
    {
        int nb = (N + ROWS - 1) / ROWS;
        k_main<<<nb, ROWS, 0, stream>>>(x, batch, WO, bo, wnorm, segsum, embs, N);
    }
    {
        int nb = (N + 255) / 256;
        k_final<<<nb, 256, 0, stream>>>(wnorm, batch, segsum, embs, N);
    }
}